// Round 5
// baseline (3312.258 us; speedup 1.0000x reference)
//
#include <hip/hip_runtime.h>
#include <math.h>

#define DM 256
#define LL 256
#define DI 512
#define NBLK 1024

// ---------------- device-scope grid barrier (generation-based) ----------------
__device__ __forceinline__ void grid_barrier(int* cnt, int* gen) {
    __syncthreads();
    if (threadIdx.x == 0) {
        int g = __hip_atomic_load(gen, __ATOMIC_ACQUIRE, __HIP_MEMORY_SCOPE_AGENT);
        int a = __hip_atomic_fetch_add(cnt, 1, __ATOMIC_ACQ_REL, __HIP_MEMORY_SCOPE_AGENT);
        if (a == NBLK - 1) {
            __hip_atomic_store(cnt, 0, __ATOMIC_RELAXED, __HIP_MEMORY_SCOPE_AGENT);
            __hip_atomic_fetch_add(gen, 1, __ATOMIC_ACQ_REL, __HIP_MEMORY_SCOPE_AGENT);
        } else {
            while (__hip_atomic_load(gen, __ATOMIC_ACQUIRE, __HIP_MEMORY_SCOPE_AGENT) == g)
                __builtin_amdgcn_s_sleep(2);
        }
    }
    __syncthreads();
}

// ---------------- 32x32-tile NT GEMM stage: C[m0:+32, n0:+32] = A[M,K]*B[N,K]^T ----------------
template<int KD>
__device__ __forceinline__ void gemm_nt_32x32(const float* __restrict__ A,
                                              const float* __restrict__ B,
                                              float* __restrict__ C,
                                              int m0, int n0, int ldc,
                                              float* As, float* Bs) {
    int tid = threadIdx.x;
    int tx = tid & 15, ty = tid >> 4;
    int r = (tid & 127) >> 2, q = tid & 3;
    const float* src = (tid < 128) ? (A + (size_t)(m0 + r) * KD)
                                   : (B + (size_t)(n0 + r) * KD);
    float* dst = (tid < 128) ? As : Bs;
    float acc00 = 0.f, acc01 = 0.f, acc10 = 0.f, acc11 = 0.f;
    for (int k0 = 0; k0 < KD; k0 += 16) {
        float4 v = *(const float4*)(src + k0 + 4 * q);
        __syncthreads();
        dst[(4 * q + 0) * 36 + r] = v.x;
        dst[(4 * q + 1) * 36 + r] = v.y;
        dst[(4 * q + 2) * 36 + r] = v.z;
        dst[(4 * q + 3) * 36 + r] = v.w;
        __syncthreads();
#pragma unroll
        for (int kk = 0; kk < 16; ++kk) {
            float2 a = *(const float2*)(As + kk * 36 + 2 * ty);
            float2 b = *(const float2*)(Bs + kk * 36 + 2 * tx);
            acc00 = fmaf(a.x, b.x, acc00);
            acc01 = fmaf(a.x, b.y, acc01);
            acc10 = fmaf(a.y, b.x, acc10);
            acc11 = fmaf(a.y, b.y, acc11);
        }
    }
    float* c0 = C + (size_t)(m0 + 2 * ty) * ldc + n0 + 2 * tx;
    c0[0] = acc00; c0[1] = acc01;
    c0[ldc] = acc10; c0[ldc + 1] = acc11;
}

// ---------------- Wf[e0:+32, k0c:+32] = in_w1[1024,256] @ out_w0[256,512] ----------------
__device__ __forceinline__ void gemm_prep_32x32(const float* __restrict__ A,
                                                const float* __restrict__ B,
                                                float* __restrict__ C,
                                                int e0, int k0c,
                                                float* As, float* Bs) {
    int tid = threadIdx.x;
    int tx = tid & 15, ty = tid >> 4;
    float acc00 = 0.f, acc01 = 0.f, acc10 = 0.f, acc11 = 0.f;
    for (int dm0 = 0; dm0 < 256; dm0 += 16) {
        float4 v;
        if (tid < 128) {
            int r = tid >> 2, q = tid & 3;
            v = *(const float4*)(A + (size_t)(e0 + r) * 256 + dm0 + 4 * q);
            __syncthreads();
            As[(4 * q + 0) * 36 + r] = v.x;
            As[(4 * q + 1) * 36 + r] = v.y;
            As[(4 * q + 2) * 36 + r] = v.z;
            As[(4 * q + 3) * 36 + r] = v.w;
        } else {
            int idx = tid - 128;
            int r = idx >> 3, q = idx & 7;
            v = *(const float4*)(B + (size_t)(dm0 + r) * 512 + k0c + 4 * q);
            __syncthreads();
            Bs[r * 36 + 4 * q + 0] = v.x;
            Bs[r * 36 + 4 * q + 1] = v.y;
            Bs[r * 36 + 4 * q + 2] = v.z;
            Bs[r * 36 + 4 * q + 3] = v.w;
        }
        __syncthreads();
#pragma unroll
        for (int kk = 0; kk < 16; ++kk) {
            float2 a = *(const float2*)(As + kk * 36 + 2 * ty);
            float2 b = *(const float2*)(Bs + kk * 36 + 2 * tx);
            acc00 = fmaf(a.x, b.x, acc00);
            acc01 = fmaf(a.x, b.y, acc01);
            acc10 = fmaf(a.y, b.x, acc10);
            acc11 = fmaf(a.y, b.y, acc11);
        }
    }
    float* c0 = C + (size_t)(e0 + 2 * ty) * 512 + k0c + 2 * tx;
    c0[0] = acc00; c0[1] = acc01;
    c0[512] = acc10; c0[513] = acc11;
}

// ---------------- selective scan for one sequence (4 waves x 4 states) ----------------
__device__ __forceinline__ void scan_seq(int seq,
                                         const float* __restrict__ xx,
                                         const float* __restrict__ xdbl,
                                         const float* __restrict__ xz,
                                         const float* __restrict__ Alog,
                                         const float* __restrict__ Dpp,
                                         const float* __restrict__ dtw,
                                         const float* __restrict__ dtb,
                                         float* __restrict__ yg,
                                         float* yred, float* us) {
    int tid = threadIdx.x;
    int lane = tid & 63, wv = tid >> 6;
    int d = seq & (DI - 1), b = seq >> 9;
    int l0 = lane * 4;

    const float* xd0 = xdbl + ((size_t)(b * LL) + l0) * 48;
    const float* wr = dtw + d * 16;
    float4 w0 = *(const float4*)(wr + 0);
    float4 w1 = *(const float4*)(wr + 4);
    float4 w2 = *(const float4*)(wr + 8);
    float4 w3 = *(const float4*)(wr + 12);
    float bias = dtb[d];

    float dt[4], u[4], dtu[4], P[4];
#pragma unroll
    for (int i = 0; i < 4; ++i) {
        const float* xr = xd0 + i * 48;
        float4 a0 = *(const float4*)(xr + 0);
        float4 a1 = *(const float4*)(xr + 4);
        float4 a2 = *(const float4*)(xr + 8);
        float4 a3 = *(const float4*)(xr + 12);
        float acc = bias;
        acc = fmaf(a0.x, w0.x, acc); acc = fmaf(a0.y, w0.y, acc);
        acc = fmaf(a0.z, w0.z, acc); acc = fmaf(a0.w, w0.w, acc);
        acc = fmaf(a1.x, w1.x, acc); acc = fmaf(a1.y, w1.y, acc);
        acc = fmaf(a1.z, w1.z, acc); acc = fmaf(a1.w, w1.w, acc);
        acc = fmaf(a2.x, w2.x, acc); acc = fmaf(a2.y, w2.y, acc);
        acc = fmaf(a2.z, w2.z, acc); acc = fmaf(a2.w, w2.w, acc);
        acc = fmaf(a3.x, w3.x, acc); acc = fmaf(a3.y, w3.y, acc);
        acc = fmaf(a3.z, w3.z, acc); acc = fmaf(a3.w, w3.w, acc);
        dt[i] = (acc > 20.0f) ? acc : log1pf(expf(acc));
        u[i] = xx[((size_t)(b * LL) + l0 + i) * DI + d];
        dtu[i] = dt[i] * u[i];
    }

    P[0] = dt[0]; P[1] = P[0] + dt[1]; P[2] = P[1] + dt[2]; P[3] = P[2] + dt[3];
    float s = P[3];
#pragma unroll
    for (int off = 1; off < 64; off <<= 1) {
        float t = __shfl_up(s, off);
        if (lane >= off) s += t;
    }
    float base = s - P[3];
    float dt_end = __shfl(s, 63);
    float Dtc[4];
#pragma unroll
    for (int i = 0; i < 4; ++i) Dtc[i] = P[i] + base;

    if (wv == 0) {
#pragma unroll
        for (int i = 0; i < 4; ++i) us[l0 + i] = u[i];
    }

    float4 Al = *(const float4*)(Alog + d * 16 + 4 * wv);
    float A[4] = {-expf(Al.x), -expf(Al.y), -expf(Al.z), -expf(Al.w)};
    float Bv[4][4], Cv[4][4];
#pragma unroll
    for (int i = 0; i < 4; ++i) {
        float4 bq = *(const float4*)(xd0 + i * 48 + 16 + 4 * wv);
        float4 cq = *(const float4*)(xd0 + i * 48 + 32 + 4 * wv);
        Bv[i][0] = bq.x; Bv[i][1] = bq.y; Bv[i][2] = bq.z; Bv[i][3] = bq.w;
        Cv[i][0] = cq.x; Cv[i][1] = cq.y; Cv[i][2] = cq.z; Cv[i][3] = cq.w;
    }

    float y[4] = {0.f, 0.f, 0.f, 0.f};
#pragma unroll
    for (int c = 0; c < 4; ++c) {
        float Ac = A[c];
        float dAc[4], t[4];
#pragma unroll
        for (int i = 0; i < 4; ++i) {
            dAc[i] = expf(Ac * (dt_end - Dtc[i]));
            t[i] = dtu[i] * Bv[i][c] * dAc[i];
        }
        float p0 = t[0], p1 = p0 + t[1], p2 = p1 + t[2], p3 = p2 + t[3];
        float ss = p3;
#pragma unroll
        for (int off = 1; off < 64; off <<= 1) {
            float tt = __shfl_up(ss, off);
            if (lane >= off) ss += tt;
        }
        float baseT = ss - p3;
        y[0] += (p0 + baseT) / (dAc[0] + 1e-12f) * Cv[0][c];
        y[1] += (p1 + baseT) / (dAc[1] + 1e-12f) * Cv[1][c];
        y[2] += (p2 + baseT) / (dAc[2] + 1e-12f) * Cv[2][c];
        y[3] += (p3 + baseT) / (dAc[3] + 1e-12f) * Cv[3][c];
    }
#pragma unroll
    for (int i = 0; i < 4; ++i) yred[wv * LL + l0 + i] = y[i];
    __syncthreads();

    int l = tid;
    float ysum = yred[0 * LL + l] + yred[1 * LL + l] + yred[2 * LL + l] + yred[3 * LL + l];
    float yv = fmaf(us[l], Dpp[d], ysum);
    float res = xz[((size_t)(b * LL) + l) * 1024 + DI + d];
    yg[((size_t)(b * LL) + l) * DI + d] = yv * (res / (1.0f + expf(-res)));
    __syncthreads();
}

// ---------------- the whole pipeline in one resident kernel ----------------
__global__ __launch_bounds__(256, 4) void k_chain(
    int mode,
    const float* __restrict__ x0,
    const float* __restrict__ in_w, const float* __restrict__ conv_w,
    const float* __restrict__ conv_b, const float* __restrict__ xproj_w,
    const float* __restrict__ dt_w, const float* __restrict__ dt_b,
    const float* __restrict__ A_log, const float* __restrict__ Dp,
    const float* __restrict__ out_w,
    float* S0, float* Sout, float* Wf,
    float* xz, float* xx, float* xdbl, float* yg,
    int* bar, float* out) {
    __shared__ float smem[1536];
    int* cnt = bar;
    int* gen = bar + 1;
    const int bl = blockIdx.x;
    const int tid = threadIdx.x;

    // ---- stage -1: mean_w (mode 0) or fuse_mean_h (mode 1) ----
    if (mode == 0) {
        int wv = tid >> 6, lane = tid & 63;
        const float4* x4 = (const float4*)x0;
        int rbase = bl * 256 + wv * 64;
        for (int i0 = 0; i0 < 64; i0 += 4) {
            float s[4];
#pragma unroll
            for (int j = 0; j < 4; ++j) {
                float4 v = x4[(size_t)(rbase + i0 + j) * 64 + lane];
                s[j] = (v.x + v.y) + (v.z + v.w);
            }
#pragma unroll
            for (int j = 0; j < 4; ++j) {
#pragma unroll
                for (int m = 32; m >= 1; m >>= 1) s[j] += __shfl_xor(s[j], m);
            }
            if (lane == 0) {
#pragma unroll
                for (int j = 0; j < 4; ++j) {
                    int rr = rbase + i0 + j;
                    int b = rr >> 16, d = (rr >> 8) & 255, h = rr & 255;
                    S0[((size_t)(b * LL) + h) * DM + d] = s[j] * (1.0f / 256.0f);
                }
            }
        }
    } else {
        int b = bl >> 8, d = bl & 255;
        float* ms = smem;
        ms[tid] = Sout[((size_t)(b * LL) + tid) * DM + d];
        __syncthreads();
        const float* xrow = x0 + (size_t)bl * 65536;
        float a0 = 0.f, a1 = 0.f, a2 = 0.f, a3 = 0.f;
        for (int h = 0; h < 256; h += 8) {
            float xv[8];
#pragma unroll
            for (int j = 0; j < 8; ++j) xv[j] = xrow[(size_t)(h + j) * 256 + tid];
            a0 = fmaf(ms[h + 0], xv[0], a0); a1 = fmaf(ms[h + 1], xv[1], a1);
            a2 = fmaf(ms[h + 2], xv[2], a2); a3 = fmaf(ms[h + 3], xv[3], a3);
            a0 = fmaf(ms[h + 4], xv[4], a0); a1 = fmaf(ms[h + 5], xv[5], a1);
            a2 = fmaf(ms[h + 6], xv[6], a2); a3 = fmaf(ms[h + 7], xv[7], a3);
        }
        S0[((size_t)(b * LL) + tid) * DM + d] = ((a0 + a1) + (a2 + a3)) * (1.0f / 256.0f);
    }
    grid_barrier(cnt, gen);

    float* As = smem;
    float* Bs = smem + 576;

    // ---- stage 0: in-proj (layer 0) + Wf prep (chain 1 only) ----
    gemm_nt_32x32<256>(S0, in_w, xz, (bl >> 5) * 32, (bl & 31) * 32, 1024, As, Bs);
    if (mode == 0 && bl < 512)
        gemm_prep_32x32(in_w + 1024 * 256, out_w, Wf, (bl >> 4) * 32, (bl & 15) * 32, As, Bs);
    grid_barrier(cnt, gen);

    for (int layer = 0; layer < 2; ++layer) {
        const float* cw = conv_w + layer * DI * 4;
        const float* cb = conv_b + layer * DI;
        const float* xpw = xproj_w + (size_t)layer * 48 * DI;
        const float* dtw = dt_w + layer * DI * 16;
        const float* dtb = dt_b + layer * DI;
        const float* Alog = A_log + layer * DI * 16;
        const float* Dpp = Dp + layer * DI;

        // ---- MID: conv+silu+xproj, block = (b,l) ----
        {
            float* xs = smem;
            float* pr = smem + 512;
            int b = bl >> 8, l = bl & 255;
#pragma unroll
            for (int c = 0; c < 2; ++c) {
                int d = tid + 256 * c;
                float4 w4 = *(const float4*)(cw + d * 4);
                float acc = cb[d];
#pragma unroll
                for (int k = 0; k < 4; ++k) {
                    int ls = l + k - 3;
                    float v = (ls >= 0) ? xz[((size_t)(b * LL + ls)) * 1024 + d] : 0.0f;
                    acc = fmaf(((const float*)&w4)[k], v, acc);
                }
                float v = acc / (1.0f + expf(-acc));
                xs[d] = v;
                xx[(size_t)bl * DI + d] = v;
            }
            __syncthreads();
            int e = tid >> 2, c2 = tid & 3;
            float a = 0.0f;
            if (e < 48) {
                const float4* xv4 = (const float4*)(xs + c2 * 128);
                const float4* wv4 = (const float4*)(xpw + (size_t)e * DI + c2 * 128);
#pragma unroll 8
                for (int qq = 0; qq < 32; ++qq) {
                    float4 x4v = xv4[qq], p4 = wv4[qq];
                    a = fmaf(x4v.x, p4.x, a);
                    a = fmaf(x4v.y, p4.y, a);
                    a = fmaf(x4v.z, p4.z, a);
                    a = fmaf(x4v.w, p4.w, a);
                }
            }
            pr[tid] = a;
            __syncthreads();
            if (tid < 48)
                xdbl[(size_t)bl * 48 + tid] =
                    pr[4 * tid] + pr[4 * tid + 1] + pr[4 * tid + 2] + pr[4 * tid + 3];
        }
        grid_barrier(cnt, gen);

        // ---- SCAN: 2 sequences per block ----
        scan_seq(bl, xx, xdbl, xz, Alog, Dpp, dtw, dtb, yg, smem, smem + 1024);
        scan_seq(bl + 1024, xx, xdbl, xz, Alog, Dpp, dtw, dtb, yg, smem, smem + 1024);
        grid_barrier(cnt, gen);

        if (layer == 0) {
            // ---- TRANS: xz = yg @ Wf^T ----
            gemm_nt_32x32<512>(yg, Wf, xz, (bl >> 5) * 32, (bl & 31) * 32, 1024, As, Bs);
            grid_barrier(cnt, gen);
        } else {
            // ---- OUT: Sout = yg @ out_w1^T ----
            if (bl < 256)
                gemm_nt_32x32<512>(yg, out_w + 256 * 512, Sout,
                                   (bl >> 3) * 32, (bl & 7) * 32, 256, As, Bs);
        }
    }

    if (mode == 1) {
        grid_barrier(cnt, gen);
        // ---- FINAL: out = Sout ⊙ x0, block = (b,d) ----
        float* ms = smem;
        int b = bl >> 8;
        int d = bl & 255;
        ms[tid] = Sout[((size_t)(b * LL) + tid) * DM + d];
        __syncthreads();
        int w4 = tid & 63, hq = tid >> 6;
        float4 mv = *(const float4*)(ms + (w4 << 2));
        const float4* xin = (const float4*)(x0 + (size_t)bl * 65536);
        float4* oo = (float4*)(out + (size_t)bl * 65536);
#pragma unroll 4
        for (int hi = 0; hi < 64; ++hi) {
            int h = hi * 4 + hq;
            size_t idx = (size_t)h * 64 + w4;
            float4 xv = xin[idx];
            float4 o;
            o.x = mv.x * xv.x; o.y = mv.y * xv.y;
            o.z = mv.z * xv.z; o.w = mv.w * xv.w;
            oo[idx] = o;
        }
    }
}

__global__ void k_init(int* bar) {
    if (threadIdx.x < 2) bar[threadIdx.x] = 0;
}

extern "C" void kernel_launch(void* const* d_in, const int* in_sizes, int n_in,
                              void* d_out, int out_size, void* d_ws, size_t ws_size,
                              hipStream_t stream) {
    const float* x0      = (const float*)d_in[0];
    const float* in_w    = (const float*)d_in[1];
    const float* conv_w  = (const float*)d_in[2];
    const float* conv_b  = (const float*)d_in[3];
    const float* xproj_w = (const float*)d_in[4];
    const float* dt_w    = (const float*)d_in[5];
    const float* dt_b    = (const float*)d_in[6];
    const float* A_log   = (const float*)d_in[7];
    const float* Dp      = (const float*)d_in[8];
    const float* out_w   = (const float*)d_in[9];
    float* out = (float*)d_out;

    float* wsf  = (float*)d_ws;
    float* S0   = wsf;                 // 262144
    float* Sout = S0 + 262144;         // 262144
    float* Wf   = Sout + 262144;       // 524288
    float* xz   = Wf + 524288;         // 1048576
    float* xx   = xz + 1048576;        // 524288
    float* xdbl = xx + 524288;         // 49152
    float* yg   = xdbl + 49152;        // 524288
    int* bar    = (int*)(yg + 524288);

    k_init<<<1, 64, 0, stream>>>(bar);
    k_chain<<<NBLK, 256, 0, stream>>>(0, x0, in_w, conv_w, conv_b, xproj_w,
                                      dt_w, dt_b, A_log, Dp, out_w,
                                      S0, Sout, Wf, xz, xx, xdbl, yg, bar, out);
    k_chain<<<NBLK, 256, 0, stream>>>(1, x0, in_w, conv_w, conv_b, xproj_w,
                                      dt_w, dt_b, A_log, Dp, out_w,
                                      S0, Sout, Wf, xz, xx, xdbl, yg, bar, out);
}

// Round 6
// 554.098 us; speedup vs baseline: 5.9778x; 5.9778x over previous
//
#include <hip/hip_runtime.h>
#include <math.h>

#define BSZ 4
#define DM 256
#define LL 256
#define DI 512
#define NBL (BSZ * LL)  // 1024

// ---------------- dispatch 1: mean over W (blocks 0..1023) + Wf prep (1024..1535) ----------------
// Wf[e,d] = sum_o in_w1[e,o] * out_w0[o,d]   (transition composition, validated r5)
__global__ __launch_bounds__(256) void k_meanw_prep(const float* __restrict__ x0,
                                                    const float* __restrict__ in_w1,
                                                    const float* __restrict__ out_w0,
                                                    float* __restrict__ S0,
                                                    float* __restrict__ Wf) {
    __shared__ float smem[1664];
    int bl = blockIdx.x;
    int tid = threadIdx.x;
    if (bl < 1024) {
        int wv = tid >> 6, lane = tid & 63;
        const float4* x4 = (const float4*)x0;
        int rbase = bl * 256 + wv * 64;
        for (int i0 = 0; i0 < 64; i0 += 4) {
            float s[4];
#pragma unroll
            for (int j = 0; j < 4; ++j) {
                float4 v = x4[(size_t)(rbase + i0 + j) * 64 + lane];
                s[j] = (v.x + v.y) + (v.z + v.w);
            }
#pragma unroll
            for (int j = 0; j < 4; ++j) {
#pragma unroll
                for (int m = 32; m >= 1; m >>= 1) s[j] += __shfl_xor(s[j], m);
            }
            if (lane == 0) {
#pragma unroll
                for (int j = 0; j < 4; ++j) {
                    int rr = rbase + i0 + j;
                    int b = rr >> 16, d = (rr >> 8) & 255, h = rr & 255;
                    S0[((size_t)(b * LL) + h) * DM + d] = s[j] * (1.0f / 256.0f);
                }
            }
        }
    } else {
        // Wf prep: 512 tiles of 32x32 over [1024 e] x [512 d], K=256 (o)
        float* As = smem;
        float* Bs = smem + 576;
        int t = bl - 1024;
        int e0 = (t >> 4) * 32, k0c = (t & 15) * 32;
        int tx = tid & 15, ty = tid >> 4;
        float acc00 = 0.f, acc01 = 0.f, acc10 = 0.f, acc11 = 0.f;
        for (int dm0 = 0; dm0 < 256; dm0 += 16) {
            float4 v;
            if (tid < 128) {
                int r = tid >> 2, q = tid & 3;
                v = *(const float4*)(in_w1 + (size_t)(e0 + r) * 256 + dm0 + 4 * q);
                __syncthreads();
                As[(4 * q + 0) * 36 + r] = v.x;
                As[(4 * q + 1) * 36 + r] = v.y;
                As[(4 * q + 2) * 36 + r] = v.z;
                As[(4 * q + 3) * 36 + r] = v.w;
            } else {
                int idx = tid - 128;
                int r = idx >> 3, q = idx & 7;
                v = *(const float4*)(out_w0 + (size_t)(dm0 + r) * 512 + k0c + 4 * q);
                __syncthreads();
                Bs[r * 36 + 4 * q + 0] = v.x;
                Bs[r * 36 + 4 * q + 1] = v.y;
                Bs[r * 36 + 4 * q + 2] = v.z;
                Bs[r * 36 + 4 * q + 3] = v.w;
            }
            __syncthreads();
#pragma unroll
            for (int kk = 0; kk < 16; ++kk) {
                float2 a = *(const float2*)(As + kk * 36 + 2 * ty);
                float2 b = *(const float2*)(Bs + kk * 36 + 2 * tx);
                acc00 = fmaf(a.x, b.x, acc00);
                acc01 = fmaf(a.x, b.y, acc01);
                acc10 = fmaf(a.y, b.x, acc10);
                acc11 = fmaf(a.y, b.y, acc11);
            }
        }
        float* c0 = Wf + (size_t)(e0 + 2 * ty) * 512 + k0c + 2 * tx;
        c0[0] = acc00; c0[1] = acc01;
        c0[512] = acc10; c0[513] = acc11;
    }
}

// ---------------- NT GEMM (in-proj): C[M,N] = A[M,K]*B[N,K]^T, tile 32x64 ----------------
__global__ __launch_bounds__(256) void k_gemm_nt32(const float* __restrict__ A,
                                                   const float* __restrict__ Bw,
                                                   float* __restrict__ C,
                                                   int M, int N, int K) {
    __shared__ float As[16][36];
    __shared__ float Bs[16][68];
    int tid = threadIdx.x;
    int tx = tid & 15, ty = tid >> 4;
    int n0 = blockIdx.x * 64;
    int m0 = blockIdx.y * 32;
    int lr = tid >> 2;
    int lk = (tid & 3) * 4;

    float acc[2][4];
#pragma unroll
    for (int i = 0; i < 2; ++i)
#pragma unroll
        for (int j = 0; j < 4; ++j) acc[i][j] = 0.0f;

    for (int k0 = 0; k0 < K; k0 += 16) {
        float4 bv = *(const float4*)(Bw + (size_t)(n0 + lr) * K + k0 + lk);
        float4 av;
        if (tid < 128) av = *(const float4*)(A + (size_t)(m0 + lr) * K + k0 + lk);
        __syncthreads();
        Bs[lk + 0][lr] = bv.x; Bs[lk + 1][lr] = bv.y; Bs[lk + 2][lr] = bv.z; Bs[lk + 3][lr] = bv.w;
        if (tid < 128) {
            As[lk + 0][lr] = av.x; As[lk + 1][lr] = av.y; As[lk + 2][lr] = av.z; As[lk + 3][lr] = av.w;
        }
        __syncthreads();
#pragma unroll
        for (int kk = 0; kk < 16; ++kk) {
            float2 a = *(const float2*)(&As[kk][2 * ty]);
            float4 bf = *(const float4*)(&Bs[kk][4 * tx]);
            acc[0][0] = fmaf(a.x, bf.x, acc[0][0]);
            acc[0][1] = fmaf(a.x, bf.y, acc[0][1]);
            acc[0][2] = fmaf(a.x, bf.z, acc[0][2]);
            acc[0][3] = fmaf(a.x, bf.w, acc[0][3]);
            acc[1][0] = fmaf(a.y, bf.x, acc[1][0]);
            acc[1][1] = fmaf(a.y, bf.y, acc[1][1]);
            acc[1][2] = fmaf(a.y, bf.z, acc[1][2]);
            acc[1][3] = fmaf(a.y, bf.w, acc[1][3]);
        }
    }
#pragma unroll
    for (int i = 0; i < 2; ++i) {
        float4 o;
        o.x = acc[i][0]; o.y = acc[i][1]; o.z = acc[i][2]; o.w = acc[i][3];
        *(float4*)(C + (size_t)(m0 + 2 * ty + i) * N + n0 + 4 * tx) = o;
    }
}

// ---------------- TN GEMM: C[m=(b,l), n] = sum_d At[(b*512+d)*256+l] * B[n*512+d] ----------------
// At = ygT [4b][512 d][256 l]; K=512. tile 32(m) x 64(n)
__global__ __launch_bounds__(256) void k_gemm_tn(const float* __restrict__ At,
                                                 const float* __restrict__ B,
                                                 float* __restrict__ C,
                                                 int ldc) {
    __shared__ float As[16 * 36];
    __shared__ float Bs[16 * 68];
    int tid = threadIdx.x;
    int tx = tid & 15, ty = tid >> 4;
    int n0 = blockIdx.x * 64;
    int m0 = blockIdx.y * 32;
    int b = m0 >> 8, l0 = m0 & 255;

    float acc[2][4];
#pragma unroll
    for (int i = 0; i < 2; ++i)
#pragma unroll
        for (int j = 0; j < 4; ++j) acc[i][j] = 0.0f;

    for (int d0 = 0; d0 < 512; d0 += 16) {
        float4 va, vb1, vb2;
        if (tid < 128) {
            int r = tid >> 3, q = tid & 7;   // r = d, q = l/4
            va = *(const float4*)(At + ((size_t)(b * 512 + d0 + r)) * 256 + l0 + 4 * q);
        } else {
            int idx = tid - 128;
            int nr = idx >> 1, q = idx & 1;  // nr = n row, q = d half
            const float* bp = B + (size_t)(n0 + nr) * 512 + d0 + 8 * q;
            vb1 = *(const float4*)(bp);
            vb2 = *(const float4*)(bp + 4);
        }
        __syncthreads();
        if (tid < 128) {
            int r = tid >> 3, q = tid & 7;
            *(float4*)(As + r * 36 + 4 * q) = va;       // As[d][l]
        } else {
            int idx = tid - 128, nr = idx >> 1, q = idx & 1;
            Bs[(8 * q + 0) * 68 + nr] = vb1.x;
            Bs[(8 * q + 1) * 68 + nr] = vb1.y;
            Bs[(8 * q + 2) * 68 + nr] = vb1.z;
            Bs[(8 * q + 3) * 68 + nr] = vb1.w;
            Bs[(8 * q + 4) * 68 + nr] = vb2.x;
            Bs[(8 * q + 5) * 68 + nr] = vb2.y;
            Bs[(8 * q + 6) * 68 + nr] = vb2.z;
            Bs[(8 * q + 7) * 68 + nr] = vb2.w;          // Bs[d][n]
        }
        __syncthreads();
#pragma unroll
        for (int kk = 0; kk < 16; ++kk) {
            float2 a = *(const float2*)(As + kk * 36 + 2 * ty);
            float4 bf = *(const float4*)(Bs + kk * 68 + 4 * tx);
            acc[0][0] = fmaf(a.x, bf.x, acc[0][0]);
            acc[0][1] = fmaf(a.x, bf.y, acc[0][1]);
            acc[0][2] = fmaf(a.x, bf.z, acc[0][2]);
            acc[0][3] = fmaf(a.x, bf.w, acc[0][3]);
            acc[1][0] = fmaf(a.y, bf.x, acc[1][0]);
            acc[1][1] = fmaf(a.y, bf.y, acc[1][1]);
            acc[1][2] = fmaf(a.y, bf.z, acc[1][2]);
            acc[1][3] = fmaf(a.y, bf.w, acc[1][3]);
        }
    }
#pragma unroll
    for (int i = 0; i < 2; ++i) {
        float4 o;
        o.x = acc[i][0]; o.y = acc[i][1]; o.z = acc[i][2]; o.w = acc[i][3];
        *(float4*)(C + (size_t)(m0 + 2 * ty + i) * ldc + n0 + 4 * tx) = o;
    }
}

// ---------------- fused conv+silu+xproj: one block per (b,l) ----------------
__global__ __launch_bounds__(256) void k_mid(const float* __restrict__ xz,
                                             const float* __restrict__ cw,
                                             const float* __restrict__ cb,
                                             const float* __restrict__ xpw,
                                             float* __restrict__ xx,
                                             float* __restrict__ xdbl) {
    __shared__ float xs[DI];
    __shared__ float pr[256];
    int bl = blockIdx.x;
    int b = bl >> 8, l = bl & 255;
    int tid = threadIdx.x;

#pragma unroll
    for (int c = 0; c < 2; ++c) {
        int d = tid + 256 * c;
        float4 w4 = *(const float4*)(cw + d * 4);
        float acc = cb[d];
#pragma unroll
        for (int k = 0; k < 4; ++k) {
            int ls = l + k - 3;
            float v = (ls >= 0) ? xz[((size_t)(b * LL + ls)) * 1024 + d] : 0.0f;
            acc = fmaf(((const float*)&w4)[k], v, acc);
        }
        float v = acc / (1.0f + expf(-acc));
        xs[d] = v;
        xx[(size_t)bl * DI + d] = v;
    }
    __syncthreads();

    int e = tid >> 2, c2 = tid & 3;
    float a = 0.0f;
    if (e < 48) {
        const float4* xv4 = (const float4*)(xs + c2 * 128);
        const float4* wv4 = (const float4*)(xpw + (size_t)e * DI + c2 * 128);
#pragma unroll 8
        for (int q = 0; q < 32; ++q) {
            float4 x4 = xv4[q], p4 = wv4[q];
            a = fmaf(x4.x, p4.x, a);
            a = fmaf(x4.y, p4.y, a);
            a = fmaf(x4.z, p4.z, a);
            a = fmaf(x4.w, p4.w, a);
        }
    }
    pr[tid] = a;
    __syncthreads();
    if (tid < 48)
        xdbl[(size_t)bl * 48 + tid] = pr[4 * tid] + pr[4 * tid + 1] + pr[4 * tid + 2] + pr[4 * tid + 3];
}

// ---------------- selective scan: block per (b,d); writes ygT coalesced ----------------
__global__ __launch_bounds__(256) void k_scan(const float* __restrict__ xx,
                                              const float* __restrict__ xdbl,
                                              const float* __restrict__ xz,
                                              const float* __restrict__ Alog,
                                              const float* __restrict__ Dp,
                                              const float* __restrict__ dtw,
                                              const float* __restrict__ dtb,
                                              float* __restrict__ ygT) {
    __shared__ float yred[4][LL];
    __shared__ float us[LL];
    int tid = threadIdx.x;
    int lane = tid & 63, w = tid >> 6;
    int seq = blockIdx.x;              // b*512 + d
    int d = seq & (DI - 1), b = seq >> 9;
    int l0 = lane * 4;

    const float* xd0 = xdbl + ((size_t)(b * LL) + l0) * 48;
    const float* wr = dtw + d * 16;
    float4 w0 = *(const float4*)(wr + 0);
    float4 w1 = *(const float4*)(wr + 4);
    float4 w2 = *(const float4*)(wr + 8);
    float4 w3 = *(const float4*)(wr + 12);
    float bias = dtb[d];

    float dt[4], u[4], dtu[4], P[4];
#pragma unroll
    for (int i = 0; i < 4; ++i) {
        const float* xr = xd0 + i * 48;
        float4 a0 = *(const float4*)(xr + 0);
        float4 a1 = *(const float4*)(xr + 4);
        float4 a2 = *(const float4*)(xr + 8);
        float4 a3 = *(const float4*)(xr + 12);
        float acc = bias;
        acc = fmaf(a0.x, w0.x, acc); acc = fmaf(a0.y, w0.y, acc);
        acc = fmaf(a0.z, w0.z, acc); acc = fmaf(a0.w, w0.w, acc);
        acc = fmaf(a1.x, w1.x, acc); acc = fmaf(a1.y, w1.y, acc);
        acc = fmaf(a1.z, w1.z, acc); acc = fmaf(a1.w, w1.w, acc);
        acc = fmaf(a2.x, w2.x, acc); acc = fmaf(a2.y, w2.y, acc);
        acc = fmaf(a2.z, w2.z, acc); acc = fmaf(a2.w, w2.w, acc);
        acc = fmaf(a3.x, w3.x, acc); acc = fmaf(a3.y, w3.y, acc);
        acc = fmaf(a3.z, w3.z, acc); acc = fmaf(a3.w, w3.w, acc);
        dt[i] = (acc > 20.0f) ? acc : log1pf(expf(acc));
        u[i] = xx[((size_t)(b * LL) + l0 + i) * DI + d];
        dtu[i] = dt[i] * u[i];
    }

    P[0] = dt[0]; P[1] = P[0] + dt[1]; P[2] = P[1] + dt[2]; P[3] = P[2] + dt[3];
    float s = P[3];
#pragma unroll
    for (int off = 1; off < 64; off <<= 1) {
        float t = __shfl_up(s, off);
        if (lane >= off) s += t;
    }
    float base = s - P[3];
    float dt_end = __shfl(s, 63);
    float Dtc[4];
#pragma unroll
    for (int i = 0; i < 4; ++i) Dtc[i] = P[i] + base;

    if (w == 0) {
#pragma unroll
        for (int i = 0; i < 4; ++i) us[l0 + i] = u[i];
    }

    float4 Al = *(const float4*)(Alog + d * 16 + 4 * w);
    float A[4] = {-expf(Al.x), -expf(Al.y), -expf(Al.z), -expf(Al.w)};
    float Bv[4][4], Cv[4][4];
#pragma unroll
    for (int i = 0; i < 4; ++i) {
        float4 bq = *(const float4*)(xd0 + i * 48 + 16 + 4 * w);
        float4 cq = *(const float4*)(xd0 + i * 48 + 32 + 4 * w);
        Bv[i][0] = bq.x; Bv[i][1] = bq.y; Bv[i][2] = bq.z; Bv[i][3] = bq.w;
        Cv[i][0] = cq.x; Cv[i][1] = cq.y; Cv[i][2] = cq.z; Cv[i][3] = cq.w;
    }

    float y[4] = {0.f, 0.f, 0.f, 0.f};
#pragma unroll
    for (int c = 0; c < 4; ++c) {
        float Ac = A[c];
        float dAc[4], t[4];
#pragma unroll
        for (int i = 0; i < 4; ++i) {
            dAc[i] = expf(Ac * (dt_end - Dtc[i]));
            t[i] = dtu[i] * Bv[i][c] * dAc[i];
        }
        float p0 = t[0], p1 = p0 + t[1], p2 = p1 + t[2], p3 = p2 + t[3];
        float ss = p3;
#pragma unroll
        for (int off = 1; off < 64; off <<= 1) {
            float tt = __shfl_up(ss, off);
            if (lane >= off) ss += tt;
        }
        float baseT = ss - p3;
        y[0] += (p0 + baseT) / (dAc[0] + 1e-12f) * Cv[0][c];
        y[1] += (p1 + baseT) / (dAc[1] + 1e-12f) * Cv[1][c];
        y[2] += (p2 + baseT) / (dAc[2] + 1e-12f) * Cv[2][c];
        y[3] += (p3 + baseT) / (dAc[3] + 1e-12f) * Cv[3][c];
    }
#pragma unroll
    for (int i = 0; i < 4; ++i) yred[w][l0 + i] = y[i];
    __syncthreads();

    int l = tid;
    float ysum = yred[0][l] + yred[1][l] + yred[2][l] + yred[3][l];
    float yv = fmaf(us[l], Dp[d], ysum);
    float res = xz[((size_t)(b * LL) + l) * 1024 + DI + d];
    ygT[(size_t)seq * LL + l] = yv * (res / (1.0f + expf(-res)));   // coalesced
}

// ---------------- phase C: x_w[b,w,dm] = mean_h( m[b,h,dm] * x0[b,dm,h,w] ) ----------------
__global__ __launch_bounds__(256) void k_fuse_mean_h(const float* __restrict__ m,
                                                     const float* __restrict__ x0,
                                                     float* __restrict__ xw) {
    int bd = blockIdx.x;
    int b = bd >> 8, d = bd & 255;
    int w = threadIdx.x;
    __shared__ float ms[LL];
    ms[w] = m[((size_t)(b * LL) + w) * DM + d];
    __syncthreads();
    const float* xrow = x0 + (size_t)bd * 65536;
    float a0 = 0.0f, a1 = 0.0f, a2 = 0.0f, a3 = 0.0f;
    for (int h = 0; h < 256; h += 8) {
        float xv[8];
#pragma unroll
        for (int j = 0; j < 8; ++j) xv[j] = xrow[(size_t)(h + j) * 256 + w];
        a0 = fmaf(ms[h + 0], xv[0], a0);
        a1 = fmaf(ms[h + 1], xv[1], a1);
        a2 = fmaf(ms[h + 2], xv[2], a2);
        a3 = fmaf(ms[h + 3], xv[3], a3);
        a0 = fmaf(ms[h + 4], xv[4], a0);
        a1 = fmaf(ms[h + 5], xv[5], a1);
        a2 = fmaf(ms[h + 6], xv[6], a2);
        a3 = fmaf(ms[h + 7], xv[7], a3);
    }
    float acc = (a0 + a1) + (a2 + a3);
    xw[((size_t)(b * LL) + w) * DM + d] = acc * (1.0f / 256.0f);
}

// ---------------- phase E: out[b,d,h,w] = mw[b,w,dm=d] * x0[b,d,h,w] ----------------
__global__ __launch_bounds__(256) void k_final(const float* __restrict__ mw,
                                               const float* __restrict__ x0,
                                               float* __restrict__ out) {
    __shared__ float ms[LL];
    int bd = blockIdx.x;
    int b = bd >> 8, d = bd & 255;
    int tid = threadIdx.x;
    ms[tid] = mw[((size_t)(b * LL) + tid) * DM + d];
    __syncthreads();

    int w4 = tid & 63;
    int hq = tid >> 6;
    float4 mv = *(const float4*)(ms + (w4 << 2));
    const float4* xin = (const float4*)(x0 + (size_t)bd * 65536);
    float4* oout = (float4*)(out + (size_t)bd * 65536);
#pragma unroll 4
    for (int hi = 0; hi < 64; ++hi) {
        int h = hi * 4 + hq;
        size_t idx = (size_t)h * 64 + w4;
        float4 xv = xin[idx];
        float4 o;
        o.x = mv.x * xv.x;
        o.y = mv.y * xv.y;
        o.z = mv.z * xv.z;
        o.w = mv.w * xv.w;
        oout[idx] = o;
    }
}

extern "C" void kernel_launch(void* const* d_in, const int* in_sizes, int n_in,
                              void* d_out, int out_size, void* d_ws, size_t ws_size,
                              hipStream_t stream) {
    const float* x0      = (const float*)d_in[0];
    const float* in_w    = (const float*)d_in[1];
    const float* conv_w  = (const float*)d_in[2];
    const float* conv_b  = (const float*)d_in[3];
    const float* xproj_w = (const float*)d_in[4];
    const float* dt_w    = (const float*)d_in[5];
    const float* dt_b    = (const float*)d_in[6];
    const float* A_log   = (const float*)d_in[7];
    const float* Dp      = (const float*)d_in[8];
    const float* out_w   = (const float*)d_in[9];
    float* out = (float*)d_out;

    float* S0   = (float*)d_ws;        // 262144
    float* Sout = S0 + 262144;         // 262144
    float* Wf   = Sout + 262144;       // 524288
    float* xz   = Wf + 524288;         // 1048576
    float* xx   = xz + 1048576;        // 524288
    float* xdbl = xx + 524288;         // 49152
    float* ygT  = xdbl + 49152;        // 524288

    const float* out_w1 = out_w + 131072;  // layer-1 out proj [256 x 512]

    auto run_model = [&](const float* inb, float* outb) {
        // layer 0 in-proj
        k_gemm_nt32<<<dim3(16, 32), 256, 0, stream>>>(inb, in_w, xz, NBL, 1024, 256);
        // layer 0 mid + scan
        k_mid<<<NBL, 256, 0, stream>>>(xz, conv_w, conv_b, xproj_w, xx, xdbl);
        k_scan<<<BSZ * DI, 256, 0, stream>>>(xx, xdbl, xz, A_log, Dp, dt_w, dt_b, ygT);
        // transition: xz(layer1) = ygT^T @ Wf^T
        k_gemm_tn<<<dim3(16, 32), 256, 0, stream>>>(ygT, Wf, xz, 1024);
        // layer 1 mid + scan
        k_mid<<<NBL, 256, 0, stream>>>(xz, conv_w + 2048, conv_b + 512,
                                       xproj_w + 24576, xx, xdbl);
        k_scan<<<BSZ * DI, 256, 0, stream>>>(xx, xdbl, xz, A_log + 8192, Dp + 512,
                                             dt_w + 8192, dt_b + 512, ygT);
        // out-proj layer 1
        k_gemm_tn<<<dim3(4, 32), 256, 0, stream>>>(ygT, out_w1, outb, 256);
    };

    // dispatch 1: mean over W + Wf prep
    k_meanw_prep<<<1536, 256, 0, stream>>>(x0, in_w + 262144, out_w, S0, Wf);
    run_model(S0, Sout);
    k_fuse_mean_h<<<NBL, 256, 0, stream>>>(Sout, x0, S0);
    run_model(S0, Sout);
    k_final<<<NBL, 256, 0, stream>>>(Sout, x0, out);
}